// Round 9
// baseline (248.742 us; speedup 1.0000x reference)
//
#include <hip/hip_runtime.h>
#include <math.h>

#define NSAMPLE 32
constexpr int B_ = 2, N_ = 8192, C_ = 64, C1_ = 128, C2_ = 128, CIN_ = 67;
constexpr float BQ_R2 = 0.15f * 0.15f;
constexpr float EPS_ = 1e-5f;

typedef __attribute__((ext_vector_type(8))) short bf16x8;
typedef __attribute__((ext_vector_type(4))) short short4v;
typedef __attribute__((ext_vector_type(4))) float f32x4;
typedef unsigned long long ull;

__device__ __forceinline__ short f2bf(float x) {            // RNE
    union { float f; unsigned u; } v; v.f = x;
    return (short)((v.u + 0x7FFFu + ((v.u >> 16) & 1u)) >> 16);
}
__device__ __forceinline__ float bf2f(short s) {
    union { float f; unsigned u; } v; v.u = ((unsigned)(unsigned short)s) << 16;
    return v.f;
}
__device__ __forceinline__ int cell_id(float x, float y, float z) {
    int cx = min((int)(x * 6.0f), 5);
    int cy = min((int)(y * 6.0f), 5);
    int cz = min((int)(z * 6.0f), 5);
    return (cz * 6 + cy) * 6 + cx;
}

// ===== Kernel A: [0,64) transpose f->fT bf16; 64: weights/BN; (64,128] count
constexpr int TBLK = (B_ * N_) / 256;        // 64

__global__ __launch_bounds__(256) void prep_kernel(
    const float* __restrict__ p, const float* __restrict__ f,
    short* __restrict__ fT, int* __restrict__ counts,
    const float* __restrict__ W1,
    const float* __restrict__ g1, const float* __restrict__ b1,
    const float* __restrict__ m1, const float* __restrict__ v1,
    const float* __restrict__ W2,
    const float* __restrict__ g2, const float* __restrict__ b2,
    const float* __restrict__ m2, const float* __restrict__ v2,
    short* __restrict__ W1fp, short* __restrict__ W2p,
    float* __restrict__ Wd, float* __restrict__ bn)
{
    int blk = blockIdx.x;
    if (blk < TBLK) {
        int g = blk * 256 + threadIdx.x;
        int b = g >> 13, n = g & (N_ - 1);
        const float* fb = f + (size_t)b * C_ * N_ + n;     // coalesced over n
        short* row = fT + (size_t)g * C_;
        #pragma unroll
        for (int c0 = 0; c0 < C_; c0 += 8) {
            bf16x8 v;
            #pragma unroll
            for (int c = 0; c < 8; ++c) v[c] = f2bf(fb[(size_t)(c0 + c) * N_]);
            *(bf16x8*)&row[c0] = v;
        }
    } else if (blk == TBLK) {
        if (threadIdx.x >= 128) return;
        int t = threadIdx.x;
        float s1 = g1[t] * rsqrtf(v1[t] + EPS_);
        float s2 = g2[t] * rsqrtf(v2[t] + EPS_);
        bn[t] = s1;            bn[128 + t] = b1[t] - m1[t] * s1;
        bn[256 + t] = s2;      bn[384 + t] = b2[t] - m2[t] * s2;
        Wd[t]       = s1 * W1[t * CIN_ + 0];    // s1-scaled dp weights (f32)
        Wd[128 + t] = s1 * W1[t * CIN_ + 1];
        Wd[256 + t] = s1 * W1[t * CIN_ + 2];
        short* r1 = W1fp + t * 64;
        for (int c = 0; c < 64; ++c) r1[c] = f2bf(W1[t * CIN_ + 3 + c]);
        short* r2 = W2p + t * C1_;
        for (int c = 0; c < C1_; ++c) r2[c] = f2bf(W2[t * C1_ + c]);
    } else {
        int g = (blk - TBLK - 1) * 256 + threadIdx.x;      // 0..B*N-1
        int b = g >> 13, n = g & (N_ - 1);
        const float* q = p + (size_t)b * N_ * 3 + 3 * n;
        int c = cell_id(q[0], q[1], q[2]);
        atomicAdd(&counts[b * 256 + c], 1);
    }
}

// ===== Kernel B: prefix sums (wave b over its 216 cells) ====================
__global__ __launch_bounds__(128) void prefix_kernel(
    const int* __restrict__ counts, int* __restrict__ starts)
{
    int w = threadIdx.x >> 6, lane = threadIdx.x & 63;
    const int* cnt = counts + w * 256;
    int* st = starts + w * 256;
    int off = 0;
    #pragma unroll
    for (int ch = 0; ch < 4; ++ch) {
        int i = ch * 64 + lane;
        int v = (i < 216) ? cnt[i] : 0;
        int incl = v;
        #pragma unroll
        for (int d = 1; d < 64; d <<= 1) {
            int t = __shfl_up(incl, d, 64);
            if (lane >= d) incl += t;
        }
        if (i <= 216) st[i] = off + incl - v;
        off += __shfl(incl, 63, 64);
    }
}

// ===== Kernel C: [0,64) scatter points into cell lists; [64,192) Y-GEMM =====
// Y[n][128ch] bf16 = s1*(W1f . f)[:,n] + sh1   (BN1 scale/shift folded)
__global__ __launch_bounds__(256) void scatter_ygemm_kernel(
    const float* __restrict__ p, const int* __restrict__ starts,
    int* __restrict__ cursors, int* __restrict__ lists,
    const short* __restrict__ fT, const short* __restrict__ W1fp,
    const float* __restrict__ bn, short* __restrict__ Y)
{
    int blk = blockIdx.x;
    if (blk < 64) {
        int g = blk * 256 + threadIdx.x;
        int b = g >> 13, n = g & (N_ - 1);
        const float* q = p + (size_t)b * N_ * 3 + 3 * n;
        int c = cell_id(q[0], q[1], q[2]);
        int slot = starts[b * 256 + c] + atomicAdd(&cursors[b * 256 + c], 1);
        lists[(b << 13) + slot] = n;
        return;
    }
    int q = blk - 64;                  // 0..127 ; 128 samples per block
    int gs0 = q * 128;
    int tid = threadIdx.x, lane = tid & 63, w = tid >> 6;
    int lr = lane & 15, lq = lane >> 4;
    int rq = (w & 1) * 64, cq = (w >> 1) * 64;   // rq: ch base, cq: sample base
    f32x4 acc[4][4];
    #pragma unroll
    for (int m = 0; m < 4; ++m)
        #pragma unroll
        for (int nt = 0; nt < 4; ++nt) acc[m][nt] = (f32x4){0.f, 0.f, 0.f, 0.f};
    #pragma unroll
    for (int ks = 0; ks < 2; ++ks) {
        bf16x8 a[4];
        #pragma unroll
        for (int m = 0; m < 4; ++m)
            a[m] = *(const bf16x8*)&W1fp[(rq + m * 16 + lr) * 64 + ks * 32 + lq * 8];
        #pragma unroll
        for (int nt = 0; nt < 4; ++nt) {
            bf16x8 bfr = *(const bf16x8*)&fT[((size_t)(gs0 + cq + nt * 16 + lr)) * 64 + ks * 32 + lq * 8];
            #pragma unroll
            for (int m = 0; m < 4; ++m)
                acc[m][nt] = __builtin_amdgcn_mfma_f32_16x16x32_bf16(a[m], bfr, acc[m][nt], 0, 0, 0);
        }
    }
    #pragma unroll
    for (int m = 0; m < 4; ++m) {
        int rb = rq + m * 16 + lq * 4;
        f32x4 sc = *(const f32x4*)&bn[rb];
        f32x4 sh = *(const f32x4*)&bn[128 + rb];
        #pragma unroll
        for (int nt = 0; nt < 4; ++nt) {
            int gs = gs0 + cq + nt * 16 + lr;
            short4v yv;
            yv[0] = f2bf(fmaf(acc[m][nt][0], sc[0], sh[0]));
            yv[1] = f2bf(fmaf(acc[m][nt][1], sc[1], sh[1]));
            yv[2] = f2bf(fmaf(acc[m][nt][2], sc[2], sh[2]));
            yv[3] = f2bf(fmaf(acc[m][nt][3], sc[3], sh[3]));
            *(short4v*)&Y[(size_t)gs * 128 + rb] = yv;
        }
    }
}

// ===== Fused: grid-query + gather/dp/ReLU staging + GEMM2 + BN2 + max =======
// 4 waves, 4 points. Wave w queries+stages its own point n0+w.
// HT LDS slot-major: [slot(16 x 16B chunks of 8ch)][128 samples][16B].
// GEMM2 swapped operands: D[sample][ch] -> cheap in-lane max epilogue.
__global__ __launch_bounds__(256) void fused_kernel(
    const float* __restrict__ p, const int* __restrict__ starts,
    const int* __restrict__ lists, const short* __restrict__ Y,
    const short* __restrict__ W2p, const float* __restrict__ Wd,
    const float* __restrict__ bn, float* __restrict__ out)
{
    __shared__ ull bitmap[4][128];          // 4KB
    __shared__ int sidx[4][NSAMPLE];        // 512B
    __shared__ short HT[16 * 128 * 8];      // 32KB slot-major

    int tid = threadIdx.x;
    int bk = blockIdx.x;
    bk = (bk & 7) * 512 + (bk >> 3);        // XCD-contiguous swizzle
    int b = bk >> 11, n0 = (bk & 2047) * 4;
    int lane = tid & 63, w = tid >> 6;
    int lr = lane & 15, lq = lane >> 4;
    const float* pb = p + (size_t)b * N_ * 3;
    const int* st = starts + b * 256;
    const int* ls = lists + (b << 13);

    // ---- grid ball-query for this wave's point ----
    int nq = n0 + w;
    float qx = pb[3 * nq], qy = pb[3 * nq + 1], qz = pb[3 * nq + 2];
    *(f32x4*)&bitmap[w][2 * lane] = (f32x4){0.f, 0.f, 0.f, 0.f};
    int cx = min((int)(qx * 6.0f), 5);
    int cy = min((int)(qy * 6.0f), 5);
    int cz = min((int)(qz * 6.0f), 5);
    int x0 = max(cx - 1, 0), x1 = min(cx + 1, 5);
    for (int s9 = 0; s9 < 9; ++s9) {
        int zz = cz - 1 + s9 / 3, yy = cy - 1 + s9 % 3;
        if (zz < 0 || zz > 5 || yy < 0 || yy > 5) continue;
        int row = (zz * 6 + yy) * 6;
        int s0 = st[row + x0];
        int len = st[row + x1 + 1] - s0;
        for (int o0 = 0; o0 < len; o0 += 64) {
            int o = o0 + lane;
            if (o < len) {
                int j = ls[s0 + o];
                float dx = __fadd_rn(pb[3 * j],     -qx);
                float dy = __fadd_rn(pb[3 * j + 1], -qy);
                float dz = __fadd_rn(pb[3 * j + 2], -qz);
                float d2 = __fadd_rn(__fadd_rn(__fmul_rn(dx, dx), __fmul_rn(dy, dy)),
                                     __fmul_rn(dz, dz));
                if (d2 < BQ_R2)
                    atomicOr(&bitmap[w][j >> 6], 1ull << (j & 63));
            }
        }
    }
    __syncthreads();

    // ---- extract 32 lowest set bits = first 32 hits by index ----
    {
        ull w0 = bitmap[w][2 * lane], w1 = bitmap[w][2 * lane + 1];
        int c = __popcll(w0) + __popcll(w1);
        int incl = c;
        #pragma unroll
        for (int d = 1; d < 64; d <<= 1) {
            int t = __shfl_up(incl, d, 64);
            if (lane >= d) incl += t;
        }
        int pref = incl - c;
        int total_hits = __shfl(incl, 63, 64);
        int rank = pref;
        ull ww = w0;
        int basebit = lane * 128;
        while (ww && rank < NSAMPLE) {
            sidx[w][rank] = basebit + __builtin_ctzll(ww);
            ++rank; ww &= ww - 1;
        }
        ww = w1; basebit += 64;
        while (ww && rank < NSAMPLE) {
            sidx[w][rank] = basebit + __builtin_ctzll(ww);
            ++rank; ww &= ww - 1;
        }
        if (total_hits < NSAMPLE) {
            ull m = __ballot(c > 0);
            int l0 = __ffsll((long long)m) - 1;
            int fb_local = w0 ? __builtin_ctzll(w0) : 64 + __builtin_ctzll(w1);
            int first = __shfl(fb_local, l0, 64) + l0 * 128;
            for (int k2 = total_hits + lane; k2 < NSAMPLE; k2 += 64) sidx[w][k2] = first;
        }
    }
    __syncthreads();

    // ---- staging: gather Y + dp correction + ReLU -> HT (bf16) ----
    {
        int sl = lane & 31, g = lane >> 5;
        int S = w * 32 + sl;
        int j = sidx[w][sl];
        float ax = __fadd_rn(pb[3 * j],     -qx);
        float ay = __fadd_rn(pb[3 * j + 1], -qy);
        float az = __fadd_rn(pb[3 * j + 2], -qz);
        const short* yrow = Y + ((size_t)((b << 13) + j)) * 128;
        #pragma unroll
        for (int pp = 0; pp < 4; ++pp) {
            int ch0 = (pp * 2 + g) * 16;
            bf16x8 ylo = *(const bf16x8*)&yrow[ch0];
            bf16x8 yhi = *(const bf16x8*)&yrow[ch0 + 8];
            union { f32x4 v[4]; float s[16]; } wxa, wya, wza;
            #pragma unroll
            for (int k = 0; k < 4; ++k) {
                wxa.v[k] = *(const f32x4*)&Wd[ch0 + 4 * k];
                wya.v[k] = *(const f32x4*)&Wd[128 + ch0 + 4 * k];
                wza.v[k] = *(const f32x4*)&Wd[256 + ch0 + 4 * k];
            }
            bf16x8 lo, hi;
            #pragma unroll
            for (int i = 0; i < 8; ++i) {
                float yv = bf2f(ylo[i]);
                float h = fmaf(az, wza.s[i], fmaf(ay, wya.s[i], fmaf(ax, wxa.s[i], yv)));
                lo[i] = f2bf(fmaxf(h, 0.f));
            }
            #pragma unroll
            for (int i = 0; i < 8; ++i) {
                float yv = bf2f(yhi[i]);
                float h = fmaf(az, wza.s[8 + i], fmaf(ay, wya.s[8 + i], fmaf(ax, wxa.s[8 + i], yv)));
                hi[i] = f2bf(fmaxf(h, 0.f));
            }
            int slot = ch0 >> 3;
            *(bf16x8*)&HT[(slot * 128 + S) * 8]       = lo;
            *(bf16x8*)&HT[((slot + 1) * 128 + S) * 8] = hi;
        }
    }
    __syncthreads();

    // ---- GEMM2 (swapped): D[sample][ch] = H . W2^T ----
    int sb = (w & 1) * 64;             // sample base (2 points)
    int wc = (w >> 1) * 64;            // out-channel base
    f32x4 acc2[4][4];
    #pragma unroll
    for (int m = 0; m < 4; ++m)
        #pragma unroll
        for (int nt = 0; nt < 4; ++nt) acc2[m][nt] = (f32x4){0.f, 0.f, 0.f, 0.f};
    #pragma unroll
    for (int ks = 0; ks < 4; ++ks) {
        bf16x8 a[4];
        #pragma unroll
        for (int m = 0; m < 4; ++m)
            a[m] = *(const bf16x8*)&HT[((ks * 4 + lq) * 128 + sb + m * 16 + lr) * 8];
        #pragma unroll
        for (int nt = 0; nt < 4; ++nt) {
            bf16x8 bw = *(const bf16x8*)&W2p[(wc + nt * 16 + lr) * C1_ + ks * 32 + lq * 8];
            #pragma unroll
            for (int m = 0; m < 4; ++m)
                acc2[m][nt] = __builtin_amdgcn_mfma_f32_16x16x32_bf16(a[m], bw, acc2[m][nt], 0, 0, 0);
        }
    }

    // ---- BN2 + max over k (in-lane + 2 shfl) + ReLU + store ----
    #pragma unroll
    for (int nt = 0; nt < 4; ++nt) {
        int ch = wc + nt * 16 + lr;
        float sc = bn[256 + ch], sh = bn[384 + ch];
        #pragma unroll
        for (int pt = 0; pt < 2; ++pt) {
            int m0 = pt * 2;
            float v =          fmaf(acc2[m0][nt][0],     sc, sh);
            v = fmaxf(v, fmaf(acc2[m0][nt][1],     sc, sh));
            v = fmaxf(v, fmaf(acc2[m0][nt][2],     sc, sh));
            v = fmaxf(v, fmaf(acc2[m0][nt][3],     sc, sh));
            v = fmaxf(v, fmaf(acc2[m0 + 1][nt][0], sc, sh));
            v = fmaxf(v, fmaf(acc2[m0 + 1][nt][1], sc, sh));
            v = fmaxf(v, fmaf(acc2[m0 + 1][nt][2], sc, sh));
            v = fmaxf(v, fmaf(acc2[m0 + 1][nt][3], sc, sh));
            v = fmaxf(v, __shfl_xor(v, 16, 64));
            v = fmaxf(v, __shfl_xor(v, 32, 64));
            if (lq == 0)
                out[((size_t)(b * C2_ + ch)) * N_ + n0 + (w & 1) * 2 + pt] = fmaxf(v, 0.f);
        }
    }
}

extern "C" void kernel_launch(void* const* d_in, const int* in_sizes, int n_in,
                              void* d_out, int out_size, void* d_ws, size_t ws_size,
                              hipStream_t stream) {
    const float* p   = (const float*)d_in[0];
    const float* f   = (const float*)d_in[1];
    const float* W1  = (const float*)d_in[2];
    const float* g1  = (const float*)d_in[3];
    const float* bb1 = (const float*)d_in[4];
    const float* m1  = (const float*)d_in[5];
    const float* v1  = (const float*)d_in[6];
    const float* W2  = (const float*)d_in[7];
    const float* g2  = (const float*)d_in[8];
    const float* bb2 = (const float*)d_in[9];
    const float* m2  = (const float*)d_in[10];
    const float* v2  = (const float*)d_in[11];
    float* out = (float*)d_out;

    char* ws = (char*)d_ws;
    short* fT   = (short*)ws;                             // 2 MB
    short* Y    = (short*)(ws + (2 << 20));               // 4 MB (bf16 [16384][128])
    char*  wb   = ws + (6 << 20);
    short* W1fp = (short*)wb;                             // 16 KB
    short* W2p  = (short*)(wb + 0x4000);                  // 32 KB
    float* Wd   = (float*)(wb + 0xC000);                  // 1.5 KB
    float* bnv  = (float*)(wb + 0xD000);                  // 2 KB
    char*  gm   = wb + 0xE000;                            // grid metadata
    int* counts  = (int*)gm;                              // 2 KB
    int* cursors = (int*)(gm + 0x800);                    // 2 KB
    int* starts  = (int*)(gm + 0x1000);                   // 2 KB
    int* lists   = (int*)(gm + 0x2000);                   // 64 KB

    hipMemsetAsync(gm, 0, 0x1000, stream);                // counts + cursors
    prep_kernel<<<TBLK + 1 + 64, 256, 0, stream>>>(
        p, f, fT, counts, W1, g1, bb1, m1, v1, W2, g2, bb2, m2, v2,
        W1fp, W2p, Wd, bnv);
    prefix_kernel<<<1, 128, 0, stream>>>(counts, starts);
    scatter_ygemm_kernel<<<64 + 128, 256, 0, stream>>>(
        p, starts, cursors, lists, fT, W1fp, bnv, Y);
    fused_kernel<<<(B_ * N_) / 4, 256, 0, stream>>>(
        p, starts, lists, Y, W2p, Wd, bnv, out);
}

// Round 12
// 199.529 us; speedup vs baseline: 1.2466x; 1.2466x over previous
//
#include <hip/hip_runtime.h>
#include <math.h>

#define NSAMPLE 32
constexpr int B_ = 2, N_ = 8192, C_ = 64, C1_ = 128, C2_ = 128, CIN_ = 67;
constexpr int KP = 96;            // padded Cin for GEMM1 (3 k-steps of 32)
constexpr int XPAD = 104;         // XT row stride (shorts)
constexpr float BQ_R2 = 0.15f * 0.15f;
constexpr float EPS_ = 1e-5f;

typedef __attribute__((ext_vector_type(8))) short bf16x8;
typedef __attribute__((ext_vector_type(4))) short short4v;
typedef __attribute__((ext_vector_type(4))) float f32x4;
typedef unsigned long long ull;

__device__ __forceinline__ short f2bf(float x) {            // RNE
    union { float f; unsigned u; } v; v.f = x;
    return (short)((v.u + 0x7FFFu + ((v.u >> 16) & 1u)) >> 16);
}
__device__ __forceinline__ int cell_id(float x, float y, float z) {
    int cx = min((int)(x * 6.0f), 5);
    int cy = min((int)(y * 6.0f), 5);
    int cz = min((int)(z * 6.0f), 5);
    return (cz * 6 + cy) * 6 + cx;
}

// ===== Kernel 1: [0,64) transpose f->fT; 64: weights/BN; 65,66: grid build ==
constexpr int TBLK = (B_ * N_) / 256;        // 64

__global__ __launch_bounds__(256) void prep_all_kernel(
    const float* __restrict__ p, const float* __restrict__ f,
    short* __restrict__ fT,
    const float* __restrict__ W1,
    const float* __restrict__ g1, const float* __restrict__ b1,
    const float* __restrict__ m1, const float* __restrict__ v1,
    const float* __restrict__ W2,
    const float* __restrict__ g2, const float* __restrict__ b2,
    const float* __restrict__ m2, const float* __restrict__ v2,
    short* __restrict__ W1p, short* __restrict__ W2p, float* __restrict__ bn,
    int* __restrict__ starts, int* __restrict__ lists)
{
    int blk = blockIdx.x;
    int tid = threadIdx.x;
    if (blk < TBLK) {
        // ---- transpose f [B,C,N] fp32 -> fT [B*N][64] bf16 ----
        int g = blk * 256 + tid;
        int b = g >> 13, n = g & (N_ - 1);
        const float* fb = f + (size_t)b * C_ * N_ + n;     // coalesced over n
        short* row = fT + (size_t)g * C_;
        #pragma unroll
        for (int c0 = 0; c0 < C_; c0 += 8) {
            bf16x8 v;
            #pragma unroll
            for (int c = 0; c < 8; ++c) v[c] = f2bf(fb[(size_t)(c0 + c) * N_]);
            *(bf16x8*)&row[c0] = v;
        }
    } else if (blk == TBLK) {
        // ---- weight / BN prep ----
        if (tid >= 128) return;
        int t = tid;
        short* r1 = W1p + t * KP;     // k 0..2 dp, 3..7 zero, 8..71 f, 72..95 zero
        #pragma unroll
        for (int k = 0; k < 3; ++k) r1[k] = f2bf(W1[t * CIN_ + k]);
        #pragma unroll
        for (int k = 3; k < 8; ++k) r1[k] = 0;
        for (int c = 0; c < 64; ++c) r1[8 + c] = f2bf(W1[t * CIN_ + 3 + c]);
        #pragma unroll
        for (int k = 72; k < KP; ++k) r1[k] = 0;
        short* r2 = W2p + t * C1_;
        for (int c = 0; c < C1_; ++c) r2[c] = f2bf(W2[t * C1_ + c]);
        float s1 = g1[t] * rsqrtf(v1[t] + EPS_);
        bn[t] = s1;            bn[128 + t] = b1[t] - m1[t] * s1;
        float s2 = g2[t] * rsqrtf(v2[t] + EPS_);
        bn[256 + t] = s2;      bn[384 + t] = b2[t] - m2[t] * s2;
    } else {
        // ---- grid build for batch bb: count + prefix + scatter, all in LDS
        __shared__ int scnt[256];
        __shared__ int scur[256];
        int bb = blk - TBLK - 1;
        const float* pbB = p + (size_t)bb * N_ * 3;
        for (int i = tid; i < 256; i += 256) scnt[i] = 0;
        __syncthreads();
        for (int n = tid; n < N_; n += 256) {
            int c = cell_id(pbB[3 * n], pbB[3 * n + 1], pbB[3 * n + 2]);
            atomicAdd(&scnt[c], 1);
        }
        __syncthreads();
        if (tid < 64) {               // wave 0: exclusive prefix over 216 cells
            int off = 0;
            #pragma unroll
            for (int ch = 0; ch < 4; ++ch) {
                int i = ch * 64 + tid;
                int v = (i < 216) ? scnt[i] : 0;
                int incl = v;
                #pragma unroll
                for (int d = 1; d < 64; d <<= 1) {
                    int t2 = __shfl_up(incl, d, 64);
                    if (tid >= d) incl += t2;
                }
                if (i <= 216) {
                    int ex = off + incl - v;
                    starts[bb * 256 + i] = ex;
                    if (i < 216) scur[i] = ex;
                }
                off += __shfl(incl, 63, 64);
            }
        }
        __syncthreads();
        for (int n = tid; n < N_; n += 256) {
            int c = cell_id(pbB[3 * n], pbB[3 * n + 1], pbB[3 * n + 2]);
            int slot = atomicAdd(&scur[c], 1);
            lists[(bb << 13) + slot] = n;
        }
    }
}

// ===== Kernel 2: grid query (round-8, known-good) ===========================
__global__ __launch_bounds__(256) void grid_query_kernel(
    const float* __restrict__ p, const int* __restrict__ starts,
    const int* __restrict__ lists, int* __restrict__ idx)
{
    __shared__ ull bitmap[4][128];
    int tid = threadIdx.x, lane = tid & 63, w = tid >> 6;
    int wid = blockIdx.x * 4 + w;             // 0..B*N-1
    int b = wid >> 13, n = wid & (N_ - 1);
    const float* pb = p + (size_t)b * N_ * 3;
    const int* st = starts + b * 256;
    const int* ls = lists + (b << 13);
    float qx = pb[3 * n], qy = pb[3 * n + 1], qz = pb[3 * n + 2];

    #pragma unroll
    for (int i = lane; i < 128; i += 64) bitmap[w][i] = 0;

    int cx = min((int)(qx * 6.0f), 5);
    int cy = min((int)(qy * 6.0f), 5);
    int cz = min((int)(qz * 6.0f), 5);
    int x0 = max(cx - 1, 0), x1 = min(cx + 1, 5);

    int segBase[9], segLen[9], total = 0;
    #pragma unroll
    for (int s = 0; s < 9; ++s) {
        int zz = cz - 1 + s / 3, yy = cy - 1 + s % 3;
        bool ok = (zz >= 0 && zz < 6 && yy >= 0 && yy < 6);
        int zc = min(max(zz, 0), 5), yc = min(max(yy, 0), 5);
        int row = (zc * 6 + yc) * 6;
        int s0 = st[row + x0], s1 = st[row + x1 + 1];
        segBase[s] = s0;
        segLen[s] = ok ? (s1 - s0) : 0;
        total += segLen[s];
    }

    for (int o0 = 0; o0 < total; o0 += 64) {
        int o = o0 + lane;
        if (o < total) {
            int rem = o, addr = -1;
            #pragma unroll
            for (int s = 0; s < 9; ++s) {
                if (rem >= 0 && rem < segLen[s] && addr < 0) addr = segBase[s] + rem;
                rem -= segLen[s];
            }
            int j = ls[addr];
            float dx = __fadd_rn(pb[3 * j],     -qx);
            float dy = __fadd_rn(pb[3 * j + 1], -qy);
            float dz = __fadd_rn(pb[3 * j + 2], -qz);
            float d2 = __fadd_rn(__fadd_rn(__fmul_rn(dx, dx), __fmul_rn(dy, dy)),
                                 __fmul_rn(dz, dz));
            if (d2 < BQ_R2)
                atomicOr(&bitmap[w][j >> 6], 1ull << (j & 63));
        }
    }
    __threadfence_block();

    ull w0 = bitmap[w][2 * lane], w1 = bitmap[w][2 * lane + 1];
    int c = __popcll(w0) + __popcll(w1);
    int incl = c;
    #pragma unroll
    for (int d = 1; d < 64; d <<= 1) {
        int t = __shfl_up(incl, d, 64);
        if (lane >= d) incl += t;
    }
    int pref = incl - c;
    int total_hits = __shfl(incl, 63, 64);
    int* out = idx + (size_t)wid * NSAMPLE;

    int rank = pref;
    ull ww = w0;
    int basebit = lane * 128;
    while (ww && rank < NSAMPLE) {
        out[rank] = basebit + __builtin_ctzll(ww);
        ++rank; ww &= ww - 1;
    }
    ww = w1; basebit += 64;
    while (ww && rank < NSAMPLE) {
        out[rank] = basebit + __builtin_ctzll(ww);
        ++rank; ww &= ww - 1;
    }

    if (total_hits < NSAMPLE) {
        ull m = __ballot(c > 0);
        int l0 = __ffsll((long long)m) - 1;
        int fb_local = w0 ? __builtin_ctzll(w0) : 64 + __builtin_ctzll(w1);
        int first = __shfl(fb_local, l0, 64) + l0 * 128;
        for (int k2 = total_hits + lane; k2 < NSAMPLE; k2 += 64) out[k2] = first;
    }
}

// ===== Kernel 3: fused gather + GEMM1 + BN1 + swapped-GEMM2 + BN2/max ======
// 4 waves, 4 points (128 sample-cols). GEMM1: wave w -> ch rows (w&1)*64,
// sample cols (w>>1)*64, XT layout [col][k] XPAD. HT slot-major
// [slot=ch/8][sample128][8ch] (32KB, unioned with XT). GEMM2 swapped:
// A=HT samples, B=W2 -> D[sample][outch]; max over k = 7 VALU + 2 shfl.
__global__ __launch_bounds__(256) void fused_mfma_kernel(
    const float* __restrict__ p, const int* __restrict__ idx,
    const short* __restrict__ fT, const short* __restrict__ W1p,
    const short* __restrict__ W2p, const float* __restrict__ bn,
    float* __restrict__ out)
{
    __shared__ short smem[16 * 128 * 8];   // 32 KB: XT (26.6KB) / HT union
    __shared__ float sBN[4][128];
    __shared__ int sidx[128];

    int tid = threadIdx.x;
    int bk = blockIdx.x;
    bk = (bk & 7) * 512 + (bk >> 3);     // XCD-contiguous swizzle (4096 = 8*512)
    int b = bk >> 11;
    int n0 = (bk & 2047) * 4;
    int lane = tid & 63, w = tid >> 6;
    int lr = lane & 15, lq = lane >> 4;

    if (tid < 128) {
        sBN[0][tid] = bn[tid];       sBN[1][tid] = bn[128 + tid];
        sBN[2][tid] = bn[256 + tid]; sBN[3][tid] = bn[384 + tid];
        sidx[tid] = idx[((size_t)((b << 13) + n0)) * NSAMPLE + tid];
    }
    __syncthreads();

    // ---- stage XT [col][k] : 8 threads per column; pads inline ----
    const float* pb = p + (size_t)b * N_ * 3;
    #pragma unroll
    for (int pass = 0; pass < 4; ++pass) {
        int col = pass * 32 + (tid >> 3);
        int part = tid & 7;
        int j = sidx[col];
        *(bf16x8*)&smem[col * XPAD + 8 + part * 8] =
            *(const bf16x8*)&fT[((size_t)(b << 13) + j) * C_ + part * 8];
        if (part == 0) {
            int n = n0 + (col >> 5);
            bf16x8 v = {0, 0, 0, 0, 0, 0, 0, 0};
            v[0] = f2bf(__fadd_rn(pb[3 * j],     -pb[3 * n]));
            v[1] = f2bf(__fadd_rn(pb[3 * j + 1], -pb[3 * n + 1]));
            v[2] = f2bf(__fadd_rn(pb[3 * j + 2], -pb[3 * n + 2]));
            *(bf16x8*)&smem[col * XPAD] = v;
        } else if (part <= 3) {
            bf16x8 z = {0, 0, 0, 0, 0, 0, 0, 0};
            *(bf16x8*)&smem[col * XPAD + 72 + (part - 1) * 8] = z;
        }
    }
    __syncthreads();

    int wr = (w & 1) * 64;   // GEMM1 ch-row base
    int wc = (w >> 1) * 64;  // GEMM1 sample-col base

    // ---- GEMM1: [128x96] x [96x128] (A=W1, B=XT) ----
    f32x4 acc[4][4];
    #pragma unroll
    for (int m = 0; m < 4; ++m)
        #pragma unroll
        for (int nt = 0; nt < 4; ++nt) acc[m][nt] = (f32x4){0.f, 0.f, 0.f, 0.f};
    #pragma unroll
    for (int ks = 0; ks < 3; ++ks) {
        bf16x8 a[4];
        #pragma unroll
        for (int m = 0; m < 4; ++m)
            a[m] = *(const bf16x8*)&W1p[(wr + m * 16 + lr) * KP + ks * 32 + lq * 8];
        #pragma unroll
        for (int nt = 0; nt < 4; ++nt) {
            bf16x8 bf = *(const bf16x8*)&smem[(wc + nt * 16 + lr) * XPAD + ks * 32 + lq * 8];
            #pragma unroll
            for (int m = 0; m < 4; ++m)
                acc[m][nt] = __builtin_amdgcn_mfma_f32_16x16x32_bf16(a[m], bf, acc[m][nt], 0, 0, 0);
        }
    }
    __syncthreads();          // all XT reads done before HT overwrites

    // ---- BN1 + ReLU -> HT slot-major [ch/8][sample][8] ----
    #pragma unroll
    for (int m = 0; m < 4; ++m) {
        int rb = wr + m * 16 + lq * 4;          // 4 consecutive ch
        float s0 = sBN[0][rb], s1 = sBN[0][rb + 1], s2 = sBN[0][rb + 2], s3 = sBN[0][rb + 3];
        float h0 = sBN[1][rb], h1 = sBN[1][rb + 1], h2 = sBN[1][rb + 2], h3 = sBN[1][rb + 3];
        #pragma unroll
        for (int nt = 0; nt < 4; ++nt) {
            int col = wc + nt * 16 + lr;        // sample
            short4v hv;
            hv[0] = f2bf(fmaxf(fmaf(acc[m][nt][0], s0, h0), 0.f));
            hv[1] = f2bf(fmaxf(fmaf(acc[m][nt][1], s1, h1), 0.f));
            hv[2] = f2bf(fmaxf(fmaf(acc[m][nt][2], s2, h2), 0.f));
            hv[3] = f2bf(fmaxf(fmaf(acc[m][nt][3], s3, h3), 0.f));
            *(short4v*)&smem[((rb >> 3) * 128 + col) * 8 + (rb & 7)] = hv;
        }
    }
    __syncthreads();

    // ---- GEMM2 swapped: D[sample][outch] = H . W2^T ----
    int sb = (w & 1) * 64;             // sample base (2 points)
    int wc2 = (w >> 1) * 64;           // out-channel base
    f32x4 acc2[4][4];
    #pragma unroll
    for (int m = 0; m < 4; ++m)
        #pragma unroll
        for (int nt = 0; nt < 4; ++nt) acc2[m][nt] = (f32x4){0.f, 0.f, 0.f, 0.f};
    #pragma unroll
    for (int ks = 0; ks < 4; ++ks) {
        bf16x8 a[4];
        #pragma unroll
        for (int m = 0; m < 4; ++m)
            a[m] = *(const bf16x8*)&smem[((ks * 4 + lq) * 128 + sb + m * 16 + lr) * 8];
        #pragma unroll
        for (int nt = 0; nt < 4; ++nt) {
            bf16x8 bw = *(const bf16x8*)&W2p[(wc2 + nt * 16 + lr) * C1_ + ks * 32 + lq * 8];
            #pragma unroll
            for (int m = 0; m < 4; ++m)
                acc2[m][nt] = __builtin_amdgcn_mfma_f32_16x16x32_bf16(a[m], bw, acc2[m][nt], 0, 0, 0);
        }
    }

    // ---- BN2 + max over k (8 in-lane + 2 shfl) + ReLU + store ----
    #pragma unroll
    for (int nt = 0; nt < 4; ++nt) {
        int ch = wc2 + nt * 16 + lr;
        float sc = sBN[2][ch], sh = sBN[3][ch];
        #pragma unroll
        for (int pt = 0; pt < 2; ++pt) {
            int m0 = pt * 2;
            float v =    fmaf(acc2[m0][nt][0],     sc, sh);
            v = fmaxf(v, fmaf(acc2[m0][nt][1],     sc, sh));
            v = fmaxf(v, fmaf(acc2[m0][nt][2],     sc, sh));
            v = fmaxf(v, fmaf(acc2[m0][nt][3],     sc, sh));
            v = fmaxf(v, fmaf(acc2[m0 + 1][nt][0], sc, sh));
            v = fmaxf(v, fmaf(acc2[m0 + 1][nt][1], sc, sh));
            v = fmaxf(v, fmaf(acc2[m0 + 1][nt][2], sc, sh));
            v = fmaxf(v, fmaf(acc2[m0 + 1][nt][3], sc, sh));
            v = fmaxf(v, __shfl_xor(v, 16, 64));
            v = fmaxf(v, __shfl_xor(v, 32, 64));
            if (lq == 0)
                out[((size_t)(b * C2_ + ch)) * N_ + n0 + (w & 1) * 2 + pt] = fmaxf(v, 0.f);
        }
    }
}

extern "C" void kernel_launch(void* const* d_in, const int* in_sizes, int n_in,
                              void* d_out, int out_size, void* d_ws, size_t ws_size,
                              hipStream_t stream) {
    const float* p   = (const float*)d_in[0];
    const float* f   = (const float*)d_in[1];
    const float* W1  = (const float*)d_in[2];
    const float* g1  = (const float*)d_in[3];
    const float* bb1 = (const float*)d_in[4];
    const float* m1  = (const float*)d_in[5];
    const float* v1  = (const float*)d_in[6];
    const float* W2  = (const float*)d_in[7];
    const float* g2  = (const float*)d_in[8];
    const float* bb2 = (const float*)d_in[9];
    const float* m2  = (const float*)d_in[10];
    const float* v2  = (const float*)d_in[11];
    float* out = (float*)d_out;

    char* ws = (char*)d_ws;
    int*   idxbuf = (int*)ws;                           // 2 MB
    short* fT  = (short*)(ws + (2 << 20));              // 2 MB
    short* W1p = (short*)(ws + (4 << 20));              // 24 KB
    short* W2p = (short*)(ws + (4 << 20) + 0x6000);     // 32 KB
    float* bnv = (float*)(ws + (4 << 20) + 0xE000);     // 2 KB
    char*  gm  = ws + (4 << 20) + 0x10000;
    int* starts  = (int*)gm;                            // 2*256 ints
    int* lists   = (int*)(gm + 0x1000);                 // 2*8192 ints

    prep_all_kernel<<<TBLK + 3, 256, 0, stream>>>(
        p, f, fT, W1, g1, bb1, m1, v1, W2, g2, bb2, m2, v2,
        W1p, W2p, bnv, starts, lists);
    grid_query_kernel<<<(B_ * N_) / 4, 256, 0, stream>>>(p, starts, lists, idxbuf);
    fused_mfma_kernel<<<(B_ * N_) / 4, 256, 0, stream>>>(
        p, idxbuf, fT, W1p, W2p, bnv, out);
}